// Round 3
// baseline (859.167 us; speedup 1.0000x reference)
//
#include <hip/hip_runtime.h>

// Problem constants (B=4, S=1024, D=1024, H=2048, E=8, TOP_K=2)
#define NTOK 4096
#define DDIM 1024
#define HDIM 2048
#define NEXP 8
#define SEQ  1024

typedef float f32x4 __attribute__((ext_vector_type(4)));
typedef __bf16 bf16x8 __attribute__((ext_vector_type(8)));
typedef unsigned short u16x8 __attribute__((ext_vector_type(8)));

__device__ __forceinline__ unsigned short f2bf(float f) {
  unsigned int u = __float_as_uint(f);
  u += 0x7fffu + ((u >> 16) & 1u);   // round-to-nearest-even
  return (unsigned short)(u >> 16);
}

__device__ __forceinline__ u16x8 pack8(const float4& a, const float4& b) {
  u16x8 r;
  r[0] = f2bf(a.x); r[1] = f2bf(a.y); r[2] = f2bf(a.z); r[3] = f2bf(a.w);
  r[4] = f2bf(b.x); r[5] = f2bf(b.y); r[6] = f2bf(b.z); r[7] = f2bf(b.w);
  return r;
}

// async global->LDS, 16B per lane; LDS dest is wave-uniform base + lane*16
__device__ __forceinline__ void gl_lds16(const unsigned short* g, unsigned short* l) {
  __builtin_amdgcn_global_load_lds(
      (__attribute__((address_space(1))) unsigned int*)g,
      (__attribute__((address_space(3))) unsigned int*)l, 16, 0, 0);
}

// ---------------- Kernel A: gating + x->bf16 + W1/W3->bf16 (fused) -------
__global__ __launch_bounds__(256) void moe_prep(
    const float* __restrict__ x, const float* __restrict__ Wg,
    const float* __restrict__ W1, const float* __restrict__ W3,
    float* __restrict__ out_gate, float* __restrict__ out_rout,
    int* __restrict__ counts, int* __restrict__ idxlist,
    float* __restrict__ wlist, unsigned short* __restrict__ xb,
    unsigned short* __restrict__ W1b, unsigned short* __restrict__ W3b) {
  if (blockIdx.x >= 1024) {
    // weight conversion role: 2048 blocks over 4M u16x8 groups (W1 then W3)
    const int base = (blockIdx.x - 1024) * 256 + threadIdx.x;
    for (int g = base; g < 4194304; g += 2048 * 256) {
      const int half = g >> 21;            // 0 = W1, 1 = W3
      const int off = g & 2097151;
      const float* src = half ? W3 : W1;
      unsigned short* dst = half ? W3b : W1b;
      const float4* s = (const float4*)src + (size_t)off * 2;
      float4 a = s[0], b = s[1];
      ((u16x8*)dst)[off] = pack8(a, b);
    }
    return;
  }
  const int wave = threadIdx.x >> 6;
  const int lane = threadIdx.x & 63;
  const int n = blockIdx.x * 4 + wave;  // 1024 blocks x 4 waves = 4096 tokens

  const float4* xp = (const float4*)(x + (size_t)n * DDIM + lane * 16);
  float4 xv0 = xp[0], xv1 = xp[1], xv2 = xp[2], xv3 = xp[3];

  // bf16 copy of x
  u16x8* xrow = (u16x8*)(xb + ((size_t)n << 10));
  xrow[lane * 2]     = pack8(xv0, xv1);
  xrow[lane * 2 + 1] = pack8(xv2, xv3);

  float acc[NEXP];
#pragma unroll
  for (int e = 0; e < NEXP; ++e) {
    const float4* wp = (const float4*)(Wg + e * DDIM + lane * 16);
    float4 w0 = wp[0], w1 = wp[1], w2 = wp[2], w3 = wp[3];
    float a = xv0.x * w0.x + xv0.y * w0.y + xv0.z * w0.z + xv0.w * w0.w;
    a += xv1.x * w1.x + xv1.y * w1.y + xv1.z * w1.z + xv1.w * w1.w;
    a += xv2.x * w2.x + xv2.y * w2.y + xv2.z * w2.z + xv2.w * w2.w;
    a += xv3.x * w3.x + xv3.y * w3.y + xv3.z * w3.z + xv3.w * w3.w;
    acc[e] = a;
  }
#pragma unroll
  for (int e = 0; e < NEXP; ++e)
    for (int off = 32; off; off >>= 1) acc[e] += __shfl_xor(acc[e], off);

  float mx = acc[0];
#pragma unroll
  for (int e = 1; e < NEXP; ++e) mx = fmaxf(mx, acc[e]);
  float ex[NEXP], s = 0.f;
#pragma unroll
  for (int e = 0; e < NEXP; ++e) { ex[e] = __expf(acc[e] - mx); s += ex[e]; }
  const float inv = 1.f / s;

  if (lane < NEXP) {
    out_gate[n * NEXP + lane] = acc[lane];
    out_rout[n * NEXP + lane] = ex[lane] * inv;
  }

  if (lane == 0) {
    int e0 = 0; float l0 = acc[0];
#pragma unroll
    for (int e = 1; e < NEXP; ++e) if (acc[e] > l0) { l0 = acc[e]; e0 = e; }
    int e1 = -1; float l1 = -1e30f;
#pragma unroll
    for (int e = 0; e < NEXP; ++e)
      if (e != e0 && acc[e] > l1) { l1 = acc[e]; e1 = e; }
    const float p0 = ex[e0], p1 = ex[e1];
    const float rinv = 1.f / (p0 + p1);
    int pos0 = atomicAdd(&counts[e0], 1);
    idxlist[e0 * NTOK + pos0] = n * 2;     wlist[e0 * NTOK + pos0] = p0 * rinv;
    int pos1 = atomicAdd(&counts[e1], 1);
    idxlist[e1 * NTOK + pos1] = n * 2 + 1; wlist[e1 * NTOK + pos1] = p1 * rinv;
  }
}

// ---------------- fp32 -> bf16 bulk convert (W2, after gemm1) ------------
__global__ __launch_bounds__(256) void f2bf_kernel(
    const float* __restrict__ src, unsigned short* __restrict__ dst, int n8) {
  for (int i = blockIdx.x * 256 + threadIdx.x; i < n8; i += gridDim.x * 256) {
    const float4* s = (const float4*)src + (size_t)i * 2;
    float4 a = s[0], b = s[1];
    ((u16x8*)dst)[i] = pack8(a, b);
  }
}

// ---------------- Kernel B: h = silu(x W1^T) * (x W3^T), gathered --------
// 128 rows x (64 W1-cols + 64 W3-cols), BK=64. LDS exactly 32 KB -> 5 blk/CU.
// XOR-chunk swizzle: data for src chunk c of row r lives at chunk c^(r&7).
__global__ __launch_bounds__(256, 5) void moe_gemm1(
    const unsigned short* __restrict__ xb, const unsigned short* __restrict__ W1b,
    const unsigned short* __restrict__ W3b, const int* __restrict__ counts,
    const int* __restrict__ idxlist, unsigned short* __restrict__ h_ws) {
  const int e = blockIdx.z;
  const int count = counts[e];
  const int m0 = blockIdx.y * 128;
  if (m0 >= count) return;
  const int n0 = blockIdx.x * 64;

  __shared__ unsigned short As[128 * 64];   // 16 KB
  __shared__ unsigned short B1s[64 * 64];   // 8 KB
  __shared__ unsigned short B3s[64 * 64];   // 8 KB  -> total 32768 B exact

  const int tid = threadIdx.x;
  const int lane = tid & 63;
  const int wave = tid >> 6;
  const int* ilp = idxlist + e * NTOK;

  const int cswz = ((lane & 7) ^ (lane >> 3)) << 3;

  const unsigned short* gA[4]; unsigned short* lA[4];
#pragma unroll
  for (int t = 0; t < 4; ++t) {
    const int rb = (wave << 5) + (t << 3);
    const int r = rb + (lane >> 3);
    const int entry = (m0 + r < count) ? ilp[m0 + r] : 0;
    gA[t] = xb + ((size_t)(entry >> 1) << 10) + cswz;
    lA[t] = &As[rb << 6];
  }
  const unsigned short* w1p = W1b + ((size_t)e << 21);
  const unsigned short* w3p = W3b + ((size_t)e << 21);
  const unsigned short* gB1[2]; const unsigned short* gB3[2];
  unsigned short* lB1[2]; unsigned short* lB3[2];
#pragma unroll
  for (int t = 0; t < 2; ++t) {
    const int rb = (wave << 4) + (t << 3);
    const int r = rb + (lane >> 3);
    gB1[t] = w1p + ((size_t)(n0 + r) << 10) + cswz;
    gB3[t] = w3p + ((size_t)(n0 + r) << 10) + cswz;
    lB1[t] = &B1s[rb << 6];
    lB3[t] = &B3s[rb << 6];
  }

  const int wm = wave >> 1, wn = wave & 1;
  const int l16 = lane & 15, quad = lane >> 4;
  const int lsw = l16 & 7;

  f32x4 acc1[4][2], acc3[4][2];
  const f32x4 zero = {0.f, 0.f, 0.f, 0.f};
#pragma unroll
  for (int i = 0; i < 4; ++i)
#pragma unroll
    for (int j = 0; j < 2; ++j) { acc1[i][j] = zero; acc3[i][j] = zero; }

  for (int k0 = 0; k0 < DDIM; k0 += 64) {
#pragma unroll
    for (int t = 0; t < 4; ++t) gl_lds16(gA[t] + k0, lA[t]);
#pragma unroll
    for (int t = 0; t < 2; ++t) {
      gl_lds16(gB1[t] + k0, lB1[t]);
      gl_lds16(gB3[t] + k0, lB3[t]);
    }
    __syncthreads();
#pragma unroll
    for (int ks = 0; ks < 2; ++ks) {
      const int co = (((ks << 2) + quad) ^ lsw) << 3;
      bf16x8 a[4], b1[2], b3[2];
#pragma unroll
      for (int i = 0; i < 4; ++i) {
        const int row = (wm << 6) + (i << 4) + l16;
        a[i] = *(const bf16x8*)&As[(row << 6) + co];
      }
#pragma unroll
      for (int j = 0; j < 2; ++j) {
        const int row = (wn << 5) + (j << 4) + l16;
        b1[j] = *(const bf16x8*)&B1s[(row << 6) + co];
        b3[j] = *(const bf16x8*)&B3s[(row << 6) + co];
      }
#pragma unroll
      for (int i = 0; i < 4; ++i)
#pragma unroll
        for (int j = 0; j < 2; ++j) {
          acc1[i][j] = __builtin_amdgcn_mfma_f32_16x16x32_bf16(a[i], b1[j], acc1[i][j], 0, 0, 0);
          acc3[i][j] = __builtin_amdgcn_mfma_f32_16x16x32_bf16(a[i], b3[j], acc3[i][j], 0, 0, 0);
        }
    }
    __syncthreads();
  }
#pragma unroll
  for (int i = 0; i < 4; ++i) {
#pragma unroll
    for (int reg = 0; reg < 4; ++reg) {
      const int rl = (wm << 6) + (i << 4) + (quad << 2) + reg;
      if (m0 + rl < count) {
        const int entry = ilp[m0 + rl];   // 16-lane broadcast load
#pragma unroll
        for (int j = 0; j < 2; ++j) {
          const float c1 = acc1[i][j][reg];
          const float c3 = acc3[i][j][reg];
          const float hv = (c1 / (1.f + __expf(-c1))) * c3;
          const int col = n0 + (wn << 5) + (j << 4) + l16;
          h_ws[(size_t)entry * HDIM + col] = f2bf(hv);
        }
      }
    }
  }
}

// ---------------- Kernel C: contrib[entry] = (h W2^T) * w ----------------
// BM=64, BN=128, BK=64: 1024 active blocks, LDS 24 KB -> 5+ blk/CU.
__global__ __launch_bounds__(256, 5) void moe_gemm2(
    const unsigned short* __restrict__ h_ws, const unsigned short* __restrict__ W2b,
    const int* __restrict__ counts, const int* __restrict__ idxlist,
    const float* __restrict__ wlist, float* __restrict__ contrib,
    float* __restrict__ clsbuf) {
  const int e = blockIdx.z;
  const int count = counts[e];
  const int m0 = blockIdx.y * 64;
  if (m0 >= count) return;
  const int n0 = blockIdx.x * 128;

  __shared__ unsigned short As[64 * 64];    // 8 KB
  __shared__ unsigned short Bs[128 * 64];   // 16 KB

  const int tid = threadIdx.x;
  const int lane = tid & 63;
  const int wave = tid >> 6;
  const int* ilp = idxlist + e * NTOK;

  const int cswz = ((lane & 7) ^ (lane >> 3)) << 3;

  const unsigned short* gA[2]; unsigned short* lA[2];
#pragma unroll
  for (int t = 0; t < 2; ++t) {
    const int rb = (wave << 4) + (t << 3);
    const int r = rb + (lane >> 3);
    const int entry = (m0 + r < count) ? ilp[m0 + r] : 0;
    gA[t] = h_ws + ((size_t)entry << 11) + cswz;
    lA[t] = &As[rb << 6];
  }
  const unsigned short* w2p = W2b + ((size_t)e << 21);
  const unsigned short* gB[4]; unsigned short* lB[4];
#pragma unroll
  for (int t = 0; t < 4; ++t) {
    const int rb = (wave << 5) + (t << 3);
    const int r = rb + (lane >> 3);
    gB[t] = w2p + ((size_t)(n0 + r) << 11) + cswz;
    lB[t] = &Bs[rb << 6];
  }

  const int wm = wave >> 1, wn = wave & 1;
  const int l16 = lane & 15, quad = lane >> 4;
  const int lsw = l16 & 7;

  f32x4 acc[2][4];
  const f32x4 zero = {0.f, 0.f, 0.f, 0.f};
#pragma unroll
  for (int i = 0; i < 2; ++i)
#pragma unroll
    for (int j = 0; j < 4; ++j) acc[i][j] = zero;

  for (int k0 = 0; k0 < HDIM; k0 += 64) {
#pragma unroll
    for (int t = 0; t < 2; ++t) gl_lds16(gA[t] + k0, lA[t]);
#pragma unroll
    for (int t = 0; t < 4; ++t) gl_lds16(gB[t] + k0, lB[t]);
    __syncthreads();
#pragma unroll
    for (int ks = 0; ks < 2; ++ks) {
      const int co = (((ks << 2) + quad) ^ lsw) << 3;
      bf16x8 a[2], b[4];
#pragma unroll
      for (int i = 0; i < 2; ++i) {
        const int row = (wm << 5) + (i << 4) + l16;
        a[i] = *(const bf16x8*)&As[(row << 6) + co];
      }
#pragma unroll
      for (int j = 0; j < 4; ++j) {
        const int row = (wn << 6) + (j << 4) + l16;
        b[j] = *(const bf16x8*)&Bs[(row << 6) + co];
      }
#pragma unroll
      for (int i = 0; i < 2; ++i)
#pragma unroll
        for (int j = 0; j < 4; ++j)
          acc[i][j] = __builtin_amdgcn_mfma_f32_16x16x32_bf16(a[i], b[j], acc[i][j], 0, 0, 0);
    }
    __syncthreads();
  }
#pragma unroll
  for (int i = 0; i < 2; ++i) {
#pragma unroll
    for (int reg = 0; reg < 4; ++reg) {
      const int rl = (wm << 5) + (i << 4) + (quad << 2) + reg;
      if (m0 + rl < count) {
        const int entry = ilp[m0 + rl];          // broadcast within 16 lanes
        const float w = wlist[e * NTOK + m0 + rl];
        const int tok = entry >> 1;
        const bool is_cls = (tok & (SEQ - 1)) == 0;
#pragma unroll
        for (int j = 0; j < 4; ++j) {
          const int col = n0 + (wn << 6) + (j << 4) + l16;
          const float v = acc[i][j][reg] * w;
          contrib[((size_t)entry << 10) + col] = v;
          if (is_cls) clsbuf[(e * 4 + (tok >> 10)) * DDIM + col] = v;
        }
      }
    }
  }
}

// ---------------- Kernel D: combine + expert logits (fused) --------------
__global__ __launch_bounds__(256) void moe_final(
    const float* __restrict__ contrib, float* __restrict__ out_final,
    const float* __restrict__ clsbuf, const float* __restrict__ Wc,
    const float* __restrict__ bcp, float* __restrict__ out_elog) {
  if (blockIdx.x == 4096) {
    __shared__ float t[32];
    const int wave = threadIdx.x >> 6;
    const int lane = threadIdx.x & 63;
    for (int p = wave; p < 32; p += 4) {  // p = e*4 + b
      const float4* vp = (const float4*)(clsbuf + (size_t)p * DDIM + lane * 16);
      const float4* wp = (const float4*)(Wc + lane * 16);
      float a = 0.f;
#pragma unroll
      for (int q = 0; q < 4; ++q) {
        float4 v = vp[q], w = wp[q];
        a += v.x * w.x + v.y * w.y + v.z * w.z + v.w * w.w;
      }
      for (int off = 32; off; off >>= 1) a += __shfl_xor(a, off);
      if (lane == 0) t[p] = a;
    }
    __syncthreads();
    if (threadIdx.x < 4) {
      const int b = threadIdx.x;
      float run = 0.f;
      const float bias = bcp[0];
#pragma unroll
      for (int e = 0; e < NEXP; ++e) {
        run += t[e * 4 + b];
        out_elog[e * 4 + b] = run + bias;
      }
    }
    return;
  }
  const int i = blockIdx.x * 256 + threadIdx.x;  // 1M float4s
  const int tok = i >> 8, c4 = i & 255;
  const float4* cp = (const float4*)contrib;
  float4 a = cp[((size_t)tok * 2) * 256 + c4];
  float4 b = cp[((size_t)tok * 2 + 1) * 256 + c4];
  float4 o; o.x = a.x + b.x; o.y = a.y + b.y; o.z = a.z + b.z; o.w = a.w + b.w;
  ((float4*)out_final)[i] = o;
}

// ---------------- Launch --------------------------------------------------
extern "C" void kernel_launch(void* const* d_in, const int* in_sizes, int n_in,
                              void* d_out, int out_size, void* d_ws, size_t ws_size,
                              hipStream_t stream) {
  const float* x  = (const float*)d_in[0];
  const float* W1 = (const float*)d_in[2];
  const float* W2 = (const float*)d_in[3];
  const float* W3 = (const float*)d_in[4];
  const float* Wg = (const float*)d_in[5];
  const float* Wc = (const float*)d_in[6];
  const float* bc = (const float*)d_in[7];

  float* out_final = (float*)d_out;                  // [4,1024,1024]
  float* out_gate  = out_final + 4194304;            // [4096, 8]
  float* out_elog  = out_gate + 32768;               // [8, 4, 1]
  float* out_rout  = out_elog + 32;                  // [4,1024,8]

  char* ws = (char*)d_ws;
  int*   counts  = (int*)ws;                               // 32 B (pad 1 KB)
  float* clsbuf  = (float*)(ws + 1024);                    // 128 KB
  int*   idxlist = (int*)(ws + 132096);                    // 128 KB
  float* wlist   = (float*)(ws + 263168);                  // 128 KB
  const size_t MB = 1u << 20;
  unsigned short* h_ws = (unsigned short*)(ws + MB);               // 32 MB
  unsigned short* xb   = (unsigned short*)(ws + 33 * MB);          // 8 MB
  unsigned short* W1b  = (unsigned short*)(ws + 41 * MB);          // 32 MB
  unsigned short* W3b  = (unsigned short*)(ws + 73 * MB);          // 32 MB
  unsigned short* W2b  = W1b;                // alias: W1b dead after gemm1
  float* contrib = (float*)(ws + 73 * MB);   // alias: W3b dead after gemm1
  // peak ws use: 105 MB

  hipMemsetAsync(ws, 0, 132096, stream);     // counts + clsbuf (one region)

  moe_prep<<<3072, 256, 0, stream>>>(x, Wg, W1, W3, out_gate, out_rout,
                                     counts, idxlist, wlist, xb, W1b, W3b);
  moe_gemm1<<<dim3(32, 32, 8), 256, 0, stream>>>(xb, W1b, W3b, counts, idxlist, h_ws);
  f2bf_kernel<<<4096, 256, 0, stream>>>(W2, W2b, 2097152);
  moe_gemm2<<<dim3(8, 64, 8), 256, 0, stream>>>(h_ws, W2b, counts, idxlist, wlist,
                                                contrib, clsbuf);
  moe_final<<<4097, 256, 0, stream>>>(contrib, out_final, clsbuf, Wc, bc, out_elog);
}

// Round 4
// 489.396 us; speedup vs baseline: 1.7556x; 1.7556x over previous
//
#include <hip/hip_runtime.h>

// Problem constants (B=4, S=1024, D=1024, H=2048, E=8, TOP_K=2)
#define NTOK 4096
#define DDIM 1024
#define HDIM 2048
#define NEXP 8
#define SEQ  1024

typedef float f32x4 __attribute__((ext_vector_type(4)));
typedef __bf16 bf16x8 __attribute__((ext_vector_type(8)));
typedef unsigned short u16x8 __attribute__((ext_vector_type(8)));

__device__ __forceinline__ unsigned short f2bf(float f) {
  unsigned int u = __float_as_uint(f);
  u += 0x7fffu + ((u >> 16) & 1u);   // round-to-nearest-even
  return (unsigned short)(u >> 16);
}

__device__ __forceinline__ u16x8 pack8(const float4& a, const float4& b) {
  u16x8 r;
  r[0] = f2bf(a.x); r[1] = f2bf(a.y); r[2] = f2bf(a.z); r[3] = f2bf(a.w);
  r[4] = f2bf(b.x); r[5] = f2bf(b.y); r[6] = f2bf(b.z); r[7] = f2bf(b.w);
  return r;
}

// async global->LDS, 16B per lane; LDS dest is wave-uniform base + lane*16
__device__ __forceinline__ void gl_lds16(const unsigned short* g, unsigned short* l) {
  __builtin_amdgcn_global_load_lds(
      (__attribute__((address_space(1))) unsigned int*)g,
      (__attribute__((address_space(3))) unsigned int*)l, 16, 0, 0);
}

// ---------------- Kernel A: gating + x->bf16 + W1/W3->bf16 (fused) -------
__global__ __launch_bounds__(256) void moe_prep(
    const float* __restrict__ x, const float* __restrict__ Wg,
    const float* __restrict__ W1, const float* __restrict__ W3,
    float* __restrict__ out_gate, float* __restrict__ out_rout,
    int* __restrict__ counts, int* __restrict__ idxlist,
    float* __restrict__ wlist, unsigned short* __restrict__ xb,
    unsigned short* __restrict__ W1b, unsigned short* __restrict__ W3b) {
  if (blockIdx.x >= 1024) {
    // weight conversion role: 2048 blocks over 4M u16x8 groups (W1 then W3)
    const int base = (blockIdx.x - 1024) * 256 + threadIdx.x;
    for (int g = base; g < 4194304; g += 2048 * 256) {
      const int half = g >> 21;            // 0 = W1, 1 = W3
      const int off = g & 2097151;
      const float* src = half ? W3 : W1;
      unsigned short* dst = half ? W3b : W1b;
      const float4* s = (const float4*)src + (size_t)off * 2;
      float4 a = s[0], b = s[1];
      ((u16x8*)dst)[off] = pack8(a, b);
    }
    return;
  }
  const int wave = threadIdx.x >> 6;
  const int lane = threadIdx.x & 63;
  const int n = blockIdx.x * 4 + wave;  // 1024 blocks x 4 waves = 4096 tokens

  const float4* xp = (const float4*)(x + (size_t)n * DDIM + lane * 16);
  float4 xv0 = xp[0], xv1 = xp[1], xv2 = xp[2], xv3 = xp[3];

  // bf16 copy of x
  u16x8* xrow = (u16x8*)(xb + ((size_t)n << 10));
  xrow[lane * 2]     = pack8(xv0, xv1);
  xrow[lane * 2 + 1] = pack8(xv2, xv3);

  float acc[NEXP];
#pragma unroll
  for (int e = 0; e < NEXP; ++e) {
    const float4* wp = (const float4*)(Wg + e * DDIM + lane * 16);
    float4 w0 = wp[0], w1 = wp[1], w2 = wp[2], w3 = wp[3];
    float a = xv0.x * w0.x + xv0.y * w0.y + xv0.z * w0.z + xv0.w * w0.w;
    a += xv1.x * w1.x + xv1.y * w1.y + xv1.z * w1.z + xv1.w * w1.w;
    a += xv2.x * w2.x + xv2.y * w2.y + xv2.z * w2.z + xv2.w * w2.w;
    a += xv3.x * w3.x + xv3.y * w3.y + xv3.z * w3.z + xv3.w * w3.w;
    acc[e] = a;
  }
#pragma unroll
  for (int e = 0; e < NEXP; ++e)
    for (int off = 32; off; off >>= 1) acc[e] += __shfl_xor(acc[e], off);

  float mx = acc[0];
#pragma unroll
  for (int e = 1; e < NEXP; ++e) mx = fmaxf(mx, acc[e]);
  float ex[NEXP], s = 0.f;
#pragma unroll
  for (int e = 0; e < NEXP; ++e) { ex[e] = __expf(acc[e] - mx); s += ex[e]; }
  const float inv = 1.f / s;

  if (lane < NEXP) {
    out_gate[n * NEXP + lane] = acc[lane];
    out_rout[n * NEXP + lane] = ex[lane] * inv;
  }

  if (lane == 0) {
    int e0 = 0; float l0 = acc[0];
#pragma unroll
    for (int e = 1; e < NEXP; ++e) if (acc[e] > l0) { l0 = acc[e]; e0 = e; }
    int e1 = -1; float l1 = -1e30f;
#pragma unroll
    for (int e = 0; e < NEXP; ++e)
      if (e != e0 && acc[e] > l1) { l1 = acc[e]; e1 = e; }
    const float p0 = ex[e0], p1 = ex[e1];
    const float rinv = 1.f / (p0 + p1);
    int pos0 = atomicAdd(&counts[e0], 1);
    idxlist[e0 * NTOK + pos0] = n * 2;     wlist[e0 * NTOK + pos0] = p0 * rinv;
    int pos1 = atomicAdd(&counts[e1], 1);
    idxlist[e1 * NTOK + pos1] = n * 2 + 1; wlist[e1 * NTOK + pos1] = p1 * rinv;
  }
}

// ---------------- fp32 -> bf16 bulk convert (W2, after gemm1) ------------
__global__ __launch_bounds__(256) void f2bf_kernel(
    const float* __restrict__ src, unsigned short* __restrict__ dst, int n8) {
  for (int i = blockIdx.x * 256 + threadIdx.x; i < n8; i += gridDim.x * 256) {
    const float4* s = (const float4*)src + (size_t)i * 2;
    float4 a = s[0], b = s[1];
    ((u16x8*)dst)[i] = pack8(a, b);
  }
}

// ---------------- Kernel B: h = silu(x W1^T) * (x W3^T), gathered --------
// 128 rows x (64 W1-cols + 64 W3-cols), BK=64. LDS exactly 32 KB.
// NOTE: no min-waves in launch_bounds — round 3 showed (256,5) caps the
// unified VGPR+AGPR file at ~102 and spills the 64 accumulator regs to
// scratch (1.9 GB HBM traffic, 4.5x slower). Natural allocation = 96 VGPR.
__global__ __launch_bounds__(256) void moe_gemm1(
    const unsigned short* __restrict__ xb, const unsigned short* __restrict__ W1b,
    const unsigned short* __restrict__ W3b, const int* __restrict__ counts,
    const int* __restrict__ idxlist, unsigned short* __restrict__ h_ws) {
  const int e = blockIdx.z;
  const int count = counts[e];
  const int m0 = blockIdx.y * 128;
  if (m0 >= count) return;
  const int n0 = blockIdx.x * 64;

  __shared__ unsigned short As[128 * 64];   // 16 KB
  __shared__ unsigned short B1s[64 * 64];   // 8 KB
  __shared__ unsigned short B3s[64 * 64];   // 8 KB  -> total 32768 B exact

  const int tid = threadIdx.x;
  const int lane = tid & 63;
  const int wave = tid >> 6;
  const int* ilp = idxlist + e * NTOK;

  // XOR-chunk swizzle: data for src chunk c of row r lives at chunk c^(r&7)
  const int cswz = ((lane & 7) ^ (lane >> 3)) << 3;

  const unsigned short* gA[4]; unsigned short* lA[4];
#pragma unroll
  for (int t = 0; t < 4; ++t) {
    const int rb = (wave << 5) + (t << 3);
    const int r = rb + (lane >> 3);
    const int entry = (m0 + r < count) ? ilp[m0 + r] : 0;
    gA[t] = xb + ((size_t)(entry >> 1) << 10) + cswz;
    lA[t] = &As[rb << 6];
  }
  const unsigned short* w1p = W1b + ((size_t)e << 21);
  const unsigned short* w3p = W3b + ((size_t)e << 21);
  const unsigned short* gB1[2]; const unsigned short* gB3[2];
  unsigned short* lB1[2]; unsigned short* lB3[2];
#pragma unroll
  for (int t = 0; t < 2; ++t) {
    const int rb = (wave << 4) + (t << 3);
    const int r = rb + (lane >> 3);
    gB1[t] = w1p + ((size_t)(n0 + r) << 10) + cswz;
    gB3[t] = w3p + ((size_t)(n0 + r) << 10) + cswz;
    lB1[t] = &B1s[rb << 6];
    lB3[t] = &B3s[rb << 6];
  }

  const int wm = wave >> 1, wn = wave & 1;
  const int l16 = lane & 15, quad = lane >> 4;
  const int lsw = l16 & 7;

  f32x4 acc1[4][2], acc3[4][2];
  const f32x4 zero = {0.f, 0.f, 0.f, 0.f};
#pragma unroll
  for (int i = 0; i < 4; ++i)
#pragma unroll
    for (int j = 0; j < 2; ++j) { acc1[i][j] = zero; acc3[i][j] = zero; }

  for (int k0 = 0; k0 < DDIM; k0 += 64) {
#pragma unroll
    for (int t = 0; t < 4; ++t) gl_lds16(gA[t] + k0, lA[t]);
#pragma unroll
    for (int t = 0; t < 2; ++t) {
      gl_lds16(gB1[t] + k0, lB1[t]);
      gl_lds16(gB3[t] + k0, lB3[t]);
    }
    __syncthreads();
#pragma unroll
    for (int ks = 0; ks < 2; ++ks) {
      const int co = (((ks << 2) + quad) ^ lsw) << 3;
      bf16x8 a[4], b1[2], b3[2];
#pragma unroll
      for (int i = 0; i < 4; ++i) {
        const int row = (wm << 6) + (i << 4) + l16;
        a[i] = *(const bf16x8*)&As[(row << 6) + co];
      }
#pragma unroll
      for (int j = 0; j < 2; ++j) {
        const int row = (wn << 5) + (j << 4) + l16;
        b1[j] = *(const bf16x8*)&B1s[(row << 6) + co];
        b3[j] = *(const bf16x8*)&B3s[(row << 6) + co];
      }
#pragma unroll
      for (int i = 0; i < 4; ++i)
#pragma unroll
        for (int j = 0; j < 2; ++j) {
          acc1[i][j] = __builtin_amdgcn_mfma_f32_16x16x32_bf16(a[i], b1[j], acc1[i][j], 0, 0, 0);
          acc3[i][j] = __builtin_amdgcn_mfma_f32_16x16x32_bf16(a[i], b3[j], acc3[i][j], 0, 0, 0);
        }
    }
    __syncthreads();
  }
#pragma unroll
  for (int i = 0; i < 4; ++i) {
#pragma unroll
    for (int reg = 0; reg < 4; ++reg) {
      const int rl = (wm << 6) + (i << 4) + (quad << 2) + reg;
      if (m0 + rl < count) {
        const int entry = ilp[m0 + rl];   // 16-lane broadcast load
#pragma unroll
        for (int j = 0; j < 2; ++j) {
          const float c1 = acc1[i][j][reg];
          const float c3 = acc3[i][j][reg];
          const float hv = (c1 / (1.f + __expf(-c1))) * c3;
          const int col = n0 + (wn << 5) + (j << 4) + l16;
          h_ws[(size_t)entry * HDIM + col] = f2bf(hv);
        }
      }
    }
  }
}

// ---------------- Kernel C: contrib[entry] = (h W2^T) * w ----------------
// BM=64, BN=128, BK=64: 1024 active blocks, LDS 24 KB. No min-waves cap.
__global__ __launch_bounds__(256) void moe_gemm2(
    const unsigned short* __restrict__ h_ws, const unsigned short* __restrict__ W2b,
    const int* __restrict__ counts, const int* __restrict__ idxlist,
    const float* __restrict__ wlist, float* __restrict__ contrib,
    float* __restrict__ clsbuf) {
  const int e = blockIdx.z;
  const int count = counts[e];
  const int m0 = blockIdx.y * 64;
  if (m0 >= count) return;
  const int n0 = blockIdx.x * 128;

  __shared__ unsigned short As[64 * 64];    // 8 KB
  __shared__ unsigned short Bs[128 * 64];   // 16 KB

  const int tid = threadIdx.x;
  const int lane = tid & 63;
  const int wave = tid >> 6;
  const int* ilp = idxlist + e * NTOK;

  const int cswz = ((lane & 7) ^ (lane >> 3)) << 3;

  const unsigned short* gA[2]; unsigned short* lA[2];
#pragma unroll
  for (int t = 0; t < 2; ++t) {
    const int rb = (wave << 4) + (t << 3);
    const int r = rb + (lane >> 3);
    const int entry = (m0 + r < count) ? ilp[m0 + r] : 0;
    gA[t] = h_ws + ((size_t)entry << 11) + cswz;
    lA[t] = &As[rb << 6];
  }
  const unsigned short* w2p = W2b + ((size_t)e << 21);
  const unsigned short* gB[4]; unsigned short* lB[4];
#pragma unroll
  for (int t = 0; t < 4; ++t) {
    const int rb = (wave << 5) + (t << 3);
    const int r = rb + (lane >> 3);
    gB[t] = w2p + ((size_t)(n0 + r) << 11) + cswz;
    lB[t] = &Bs[rb << 6];
  }

  const int wm = wave >> 1, wn = wave & 1;
  const int l16 = lane & 15, quad = lane >> 4;
  const int lsw = l16 & 7;

  f32x4 acc[2][4];
  const f32x4 zero = {0.f, 0.f, 0.f, 0.f};
#pragma unroll
  for (int i = 0; i < 2; ++i)
#pragma unroll
    for (int j = 0; j < 4; ++j) acc[i][j] = zero;

  for (int k0 = 0; k0 < HDIM; k0 += 64) {
#pragma unroll
    for (int t = 0; t < 2; ++t) gl_lds16(gA[t] + k0, lA[t]);
#pragma unroll
    for (int t = 0; t < 4; ++t) gl_lds16(gB[t] + k0, lB[t]);
    __syncthreads();
#pragma unroll
    for (int ks = 0; ks < 2; ++ks) {
      const int co = (((ks << 2) + quad) ^ lsw) << 3;
      bf16x8 a[2], b[4];
#pragma unroll
      for (int i = 0; i < 2; ++i) {
        const int row = (wm << 5) + (i << 4) + l16;
        a[i] = *(const bf16x8*)&As[(row << 6) + co];
      }
#pragma unroll
      for (int j = 0; j < 4; ++j) {
        const int row = (wn << 6) + (j << 4) + l16;
        b[j] = *(const bf16x8*)&Bs[(row << 6) + co];
      }
#pragma unroll
      for (int i = 0; i < 2; ++i)
#pragma unroll
        for (int j = 0; j < 4; ++j)
          acc[i][j] = __builtin_amdgcn_mfma_f32_16x16x32_bf16(a[i], b[j], acc[i][j], 0, 0, 0);
    }
    __syncthreads();
  }
#pragma unroll
  for (int i = 0; i < 2; ++i) {
#pragma unroll
    for (int reg = 0; reg < 4; ++reg) {
      const int rl = (wm << 5) + (i << 4) + (quad << 2) + reg;
      if (m0 + rl < count) {
        const int entry = ilp[m0 + rl];          // broadcast within 16 lanes
        const float w = wlist[e * NTOK + m0 + rl];
        const int tok = entry >> 1;
        const bool is_cls = (tok & (SEQ - 1)) == 0;
#pragma unroll
        for (int j = 0; j < 4; ++j) {
          const int col = n0 + (wn << 6) + (j << 4) + l16;
          const float v = acc[i][j][reg] * w;
          contrib[((size_t)entry << 10) + col] = v;
          if (is_cls) clsbuf[(e * 4 + (tok >> 10)) * DDIM + col] = v;
        }
      }
    }
  }
}

// ---------------- Kernel D: combine + expert logits (fused) --------------
__global__ __launch_bounds__(256) void moe_final(
    const float* __restrict__ contrib, float* __restrict__ out_final,
    const float* __restrict__ clsbuf, const float* __restrict__ Wc,
    const float* __restrict__ bcp, float* __restrict__ out_elog) {
  if (blockIdx.x == 4096) {
    __shared__ float t[32];
    const int wave = threadIdx.x >> 6;
    const int lane = threadIdx.x & 63;
    for (int p = wave; p < 32; p += 4) {  // p = e*4 + b
      const float4* vp = (const float4*)(clsbuf + (size_t)p * DDIM + lane * 16);
      const float4* wp = (const float4*)(Wc + lane * 16);
      float a = 0.f;
#pragma unroll
      for (int q = 0; q < 4; ++q) {
        float4 v = vp[q], w = wp[q];
        a += v.x * w.x + v.y * w.y + v.z * w.z + v.w * w.w;
      }
      for (int off = 32; off; off >>= 1) a += __shfl_xor(a, off);
      if (lane == 0) t[p] = a;
    }
    __syncthreads();
    if (threadIdx.x < 4) {
      const int b = threadIdx.x;
      float run = 0.f;
      const float bias = bcp[0];
#pragma unroll
      for (int e = 0; e < NEXP; ++e) {
        run += t[e * 4 + b];
        out_elog[e * 4 + b] = run + bias;
      }
    }
    return;
  }
  const int i = blockIdx.x * 256 + threadIdx.x;  // 1M float4s
  const int tok = i >> 8, c4 = i & 255;
  const float4* cp = (const float4*)contrib;
  float4 a = cp[((size_t)tok * 2) * 256 + c4];
  float4 b = cp[((size_t)tok * 2 + 1) * 256 + c4];
  float4 o; o.x = a.x + b.x; o.y = a.y + b.y; o.z = a.z + b.z; o.w = a.w + b.w;
  ((float4*)out_final)[i] = o;
}

// ---------------- Launch --------------------------------------------------
extern "C" void kernel_launch(void* const* d_in, const int* in_sizes, int n_in,
                              void* d_out, int out_size, void* d_ws, size_t ws_size,
                              hipStream_t stream) {
  const float* x  = (const float*)d_in[0];
  const float* W1 = (const float*)d_in[2];
  const float* W2 = (const float*)d_in[3];
  const float* W3 = (const float*)d_in[4];
  const float* Wg = (const float*)d_in[5];
  const float* Wc = (const float*)d_in[6];
  const float* bc = (const float*)d_in[7];

  float* out_final = (float*)d_out;                  // [4,1024,1024]
  float* out_gate  = out_final + 4194304;            // [4096, 8]
  float* out_elog  = out_gate + 32768;               // [8, 4, 1]
  float* out_rout  = out_elog + 32;                  // [4,1024,8]

  char* ws = (char*)d_ws;
  int*   counts  = (int*)ws;                               // 32 B (pad 1 KB)
  float* clsbuf  = (float*)(ws + 1024);                    // 128 KB
  int*   idxlist = (int*)(ws + 132096);                    // 128 KB
  float* wlist   = (float*)(ws + 263168);                  // 128 KB
  const size_t MB = 1u << 20;
  unsigned short* h_ws = (unsigned short*)(ws + MB);               // 32 MB
  unsigned short* xb   = (unsigned short*)(ws + 33 * MB);          // 8 MB
  unsigned short* W1b  = (unsigned short*)(ws + 41 * MB);          // 32 MB
  unsigned short* W3b  = (unsigned short*)(ws + 73 * MB);          // 32 MB
  unsigned short* W2b  = W1b;                // alias: W1b dead after gemm1
  float* contrib = (float*)(ws + 73 * MB);   // alias: W3b dead after gemm1
  // peak ws use: 105 MB

  hipMemsetAsync(ws, 0, 132096, stream);     // counts + clsbuf (one region)

  moe_prep<<<3072, 256, 0, stream>>>(x, Wg, W1, W3, out_gate, out_rout,
                                     counts, idxlist, wlist, xb, W1b, W3b);
  moe_gemm1<<<dim3(32, 32, 8), 256, 0, stream>>>(xb, W1b, W3b, counts, idxlist, h_ws);
  f2bf_kernel<<<4096, 256, 0, stream>>>(W2, W2b, 2097152);
  moe_gemm2<<<dim3(8, 64, 8), 256, 0, stream>>>(h_ws, W2b, counts, idxlist, wlist,
                                                contrib, clsbuf);
  moe_final<<<4097, 256, 0, stream>>>(contrib, out_final, clsbuf, Wc, bc, out_elog);
}

// Round 5
// 414.600 us; speedup vs baseline: 2.0723x; 1.1804x over previous
//
#include <hip/hip_runtime.h>

// Problem constants (B=4, S=1024, D=1024, H=2048, E=8, TOP_K=2)
#define NTOK 4096
#define DDIM 1024
#define HDIM 2048
#define NEXP 8
#define SEQ  1024

typedef float f32x4 __attribute__((ext_vector_type(4)));
typedef __bf16 bf16x8 __attribute__((ext_vector_type(8)));
typedef unsigned short u16x8 __attribute__((ext_vector_type(8)));

__device__ __forceinline__ unsigned short f2bf(float f) {
  unsigned int u = __float_as_uint(f);
  u += 0x7fffu + ((u >> 16) & 1u);   // round-to-nearest-even
  return (unsigned short)(u >> 16);
}

__device__ __forceinline__ u16x8 pack8(const float4& a, const float4& b) {
  u16x8 r;
  r[0] = f2bf(a.x); r[1] = f2bf(a.y); r[2] = f2bf(a.z); r[3] = f2bf(a.w);
  r[4] = f2bf(b.x); r[5] = f2bf(b.y); r[6] = f2bf(b.z); r[7] = f2bf(b.w);
  return r;
}

// async global->LDS, 16B per lane; LDS dest is wave-uniform base + lane*16
__device__ __forceinline__ void gl_lds16(const unsigned short* g, unsigned short* l) {
  __builtin_amdgcn_global_load_lds(
      (__attribute__((address_space(1))) unsigned int*)g,
      (__attribute__((address_space(3))) unsigned int*)l, 16, 0, 0);
}

// ---------------- Kernel A: gating + x->bf16 + W1/W3->bf16 (fused) -------
// Gating: 256 blocks x 16 tokens. Per-block LDS histogram -> ONE global
// atomic per expert per block on line-padded counters (counts[e*32]).
// Round-4 lesson: 8192 same-line global atomics serialized ~110 us.
__global__ __launch_bounds__(256) void moe_prep(
    const float* __restrict__ x, const float* __restrict__ Wg,
    const float* __restrict__ W1, const float* __restrict__ W3,
    float* __restrict__ out_gate, float* __restrict__ out_rout,
    int* __restrict__ counts, int* __restrict__ idxlist,
    float* __restrict__ wlist, unsigned short* __restrict__ xb,
    unsigned short* __restrict__ W1b, unsigned short* __restrict__ W3b) {
  if (blockIdx.x >= 256) {
    // weight conversion role: 2048 blocks over 4M u16x8 groups (W1 then W3)
    const int base = (blockIdx.x - 256) * 256 + threadIdx.x;
    for (int g = base; g < 4194304; g += 2048 * 256) {
      const int half = g >> 21;            // 0 = W1, 1 = W3
      const int off = g & 2097151;
      const float* src = half ? W3 : W1;
      unsigned short* dst = half ? W3b : W1b;
      const float4* s = (const float4*)src + (size_t)off * 2;
      float4 a = s[0], b = s[1];
      ((u16x8*)dst)[off] = pack8(a, b);
    }
    return;
  }
  __shared__ int hist[NEXP];
  __shared__ int base_s[NEXP];
  const int tid = threadIdx.x;
  const int wave = tid >> 6;
  const int lane = tid & 63;
  if (tid < NEXP) hist[tid] = 0;
  __syncthreads();

  int te0[4], te1[4], ts0[4], ts1[4];
  float tw0[4], tw1[4];

#pragma unroll
  for (int t = 0; t < 4; ++t) {
    const int n = blockIdx.x * 16 + wave * 4 + t;
    const float4* xp = (const float4*)(x + (size_t)n * DDIM + lane * 16);
    float4 xv0 = xp[0], xv1 = xp[1], xv2 = xp[2], xv3 = xp[3];

    // bf16 copy of x
    u16x8* xrow = (u16x8*)(xb + ((size_t)n << 10));
    xrow[lane * 2]     = pack8(xv0, xv1);
    xrow[lane * 2 + 1] = pack8(xv2, xv3);

    float acc[NEXP];
#pragma unroll
    for (int e = 0; e < NEXP; ++e) {
      const float4* wp = (const float4*)(Wg + e * DDIM + lane * 16);
      float4 w0 = wp[0], w1 = wp[1], w2 = wp[2], w3 = wp[3];
      float a = xv0.x * w0.x + xv0.y * w0.y + xv0.z * w0.z + xv0.w * w0.w;
      a += xv1.x * w1.x + xv1.y * w1.y + xv1.z * w1.z + xv1.w * w1.w;
      a += xv2.x * w2.x + xv2.y * w2.y + xv2.z * w2.z + xv2.w * w2.w;
      a += xv3.x * w3.x + xv3.y * w3.y + xv3.z * w3.z + xv3.w * w3.w;
      acc[e] = a;
    }
#pragma unroll
    for (int e = 0; e < NEXP; ++e)
      for (int off = 32; off; off >>= 1) acc[e] += __shfl_xor(acc[e], off);

    float mx = acc[0];
#pragma unroll
    for (int e = 1; e < NEXP; ++e) mx = fmaxf(mx, acc[e]);
    float ex[NEXP], s = 0.f;
#pragma unroll
    for (int e = 0; e < NEXP; ++e) { ex[e] = __expf(acc[e] - mx); s += ex[e]; }
    const float inv = 1.f / s;

    if (lane < NEXP) {
      out_gate[n * NEXP + lane] = acc[lane];
      out_rout[n * NEXP + lane] = ex[lane] * inv;
    }

    if (lane == 0) {
      int e0 = 0; float l0 = acc[0];
#pragma unroll
      for (int e = 1; e < NEXP; ++e) if (acc[e] > l0) { l0 = acc[e]; e0 = e; }
      int e1 = -1; float l1 = -1e30f;
#pragma unroll
      for (int e = 0; e < NEXP; ++e)
        if (e != e0 && acc[e] > l1) { l1 = acc[e]; e1 = e; }
      const float p0 = ex[e0], p1 = ex[e1];
      const float rinv = 1.f / (p0 + p1);
      te0[t] = e0; te1[t] = e1;
      tw0[t] = p0 * rinv; tw1[t] = p1 * rinv;
      ts0[t] = atomicAdd(&hist[e0], 1);   // LDS atomic: block-local slot
      ts1[t] = atomicAdd(&hist[e1], 1);
    }
  }
  __syncthreads();
  if (tid < NEXP) base_s[tid] = atomicAdd(&counts[tid * 32], hist[tid]);
  __syncthreads();
  if (lane == 0) {
#pragma unroll
    for (int t = 0; t < 4; ++t) {
      const int n = blockIdx.x * 16 + wave * 4 + t;
      const int p0 = base_s[te0[t]] + ts0[t];
      const int p1 = base_s[te1[t]] + ts1[t];
      idxlist[te0[t] * NTOK + p0] = n * 2;     wlist[te0[t] * NTOK + p0] = tw0[t];
      idxlist[te1[t] * NTOK + p1] = n * 2 + 1; wlist[te1[t] * NTOK + p1] = tw1[t];
    }
  }
}

// ---------------- fp32 -> bf16 bulk convert (W2, after gemm1) ------------
__global__ __launch_bounds__(256) void f2bf_kernel(
    const float* __restrict__ src, unsigned short* __restrict__ dst, int n8) {
  for (int i = blockIdx.x * 256 + threadIdx.x; i < n8; i += gridDim.x * 256) {
    const float4* s = (const float4*)src + (size_t)i * 2;
    float4 a = s[0], b = s[1];
    ((u16x8*)dst)[i] = pack8(a, b);
  }
}

// ---------------- Kernel B: h = silu(x W1^T) * (x W3^T), gathered --------
// 128 rows x (64 W1-cols + 64 W3-cols), BK=64. LDS exactly 32 KB.
// NOTE: no min-waves in launch_bounds — round 3 showed (256,5) caps the
// unified VGPR+AGPR file at ~102 and spills the 64 accumulator regs to
// scratch (1.9 GB HBM traffic, 4.5x slower). Natural allocation = 96 VGPR.
__global__ __launch_bounds__(256) void moe_gemm1(
    const unsigned short* __restrict__ xb, const unsigned short* __restrict__ W1b,
    const unsigned short* __restrict__ W3b, const int* __restrict__ counts,
    const int* __restrict__ idxlist, unsigned short* __restrict__ h_ws) {
  const int e = blockIdx.z;
  const int count = counts[e * 32];
  const int m0 = blockIdx.y * 128;
  if (m0 >= count) return;
  const int n0 = blockIdx.x * 64;

  __shared__ unsigned short As[128 * 64];   // 16 KB
  __shared__ unsigned short B1s[64 * 64];   // 8 KB
  __shared__ unsigned short B3s[64 * 64];   // 8 KB  -> total 32768 B exact

  const int tid = threadIdx.x;
  const int lane = tid & 63;
  const int wave = tid >> 6;
  const int* ilp = idxlist + e * NTOK;

  // XOR-chunk swizzle: data for src chunk c of row r lives at chunk c^(r&7)
  const int cswz = ((lane & 7) ^ (lane >> 3)) << 3;

  const unsigned short* gA[4]; unsigned short* lA[4];
#pragma unroll
  for (int t = 0; t < 4; ++t) {
    const int rb = (wave << 5) + (t << 3);
    const int r = rb + (lane >> 3);
    const int entry = (m0 + r < count) ? ilp[m0 + r] : 0;
    gA[t] = xb + ((size_t)(entry >> 1) << 10) + cswz;
    lA[t] = &As[rb << 6];
  }
  const unsigned short* w1p = W1b + ((size_t)e << 21);
  const unsigned short* w3p = W3b + ((size_t)e << 21);
  const unsigned short* gB1[2]; const unsigned short* gB3[2];
  unsigned short* lB1[2]; unsigned short* lB3[2];
#pragma unroll
  for (int t = 0; t < 2; ++t) {
    const int rb = (wave << 4) + (t << 3);
    const int r = rb + (lane >> 3);
    gB1[t] = w1p + ((size_t)(n0 + r) << 10) + cswz;
    gB3[t] = w3p + ((size_t)(n0 + r) << 10) + cswz;
    lB1[t] = &B1s[rb << 6];
    lB3[t] = &B3s[rb << 6];
  }

  const int wm = wave >> 1, wn = wave & 1;
  const int l16 = lane & 15, quad = lane >> 4;
  const int lsw = l16 & 7;

  f32x4 acc1[4][2], acc3[4][2];
  const f32x4 zero = {0.f, 0.f, 0.f, 0.f};
#pragma unroll
  for (int i = 0; i < 4; ++i)
#pragma unroll
    for (int j = 0; j < 2; ++j) { acc1[i][j] = zero; acc3[i][j] = zero; }

  for (int k0 = 0; k0 < DDIM; k0 += 64) {
#pragma unroll
    for (int t = 0; t < 4; ++t) gl_lds16(gA[t] + k0, lA[t]);
#pragma unroll
    for (int t = 0; t < 2; ++t) {
      gl_lds16(gB1[t] + k0, lB1[t]);
      gl_lds16(gB3[t] + k0, lB3[t]);
    }
    __syncthreads();
#pragma unroll
    for (int ks = 0; ks < 2; ++ks) {
      const int co = (((ks << 2) + quad) ^ lsw) << 3;
      bf16x8 a[4], b1[2], b3[2];
#pragma unroll
      for (int i = 0; i < 4; ++i) {
        const int row = (wm << 6) + (i << 4) + l16;
        a[i] = *(const bf16x8*)&As[(row << 6) + co];
      }
#pragma unroll
      for (int j = 0; j < 2; ++j) {
        const int row = (wn << 5) + (j << 4) + l16;
        b1[j] = *(const bf16x8*)&B1s[(row << 6) + co];
        b3[j] = *(const bf16x8*)&B3s[(row << 6) + co];
      }
#pragma unroll
      for (int i = 0; i < 4; ++i)
#pragma unroll
        for (int j = 0; j < 2; ++j) {
          acc1[i][j] = __builtin_amdgcn_mfma_f32_16x16x32_bf16(a[i], b1[j], acc1[i][j], 0, 0, 0);
          acc3[i][j] = __builtin_amdgcn_mfma_f32_16x16x32_bf16(a[i], b3[j], acc3[i][j], 0, 0, 0);
        }
    }
    __syncthreads();
  }
#pragma unroll
  for (int i = 0; i < 4; ++i) {
#pragma unroll
    for (int reg = 0; reg < 4; ++reg) {
      const int rl = (wm << 6) + (i << 4) + (quad << 2) + reg;
      if (m0 + rl < count) {
        const int entry = ilp[m0 + rl];   // 16-lane broadcast load
#pragma unroll
        for (int j = 0; j < 2; ++j) {
          const float c1 = acc1[i][j][reg];
          const float c3 = acc3[i][j][reg];
          const float hv = (c1 / (1.f + __expf(-c1))) * c3;
          const int col = n0 + (wn << 5) + (j << 4) + l16;
          h_ws[(size_t)entry * HDIM + col] = f2bf(hv);
        }
      }
    }
  }
}

// ---------------- Kernel C: contrib[entry] = (h W2^T) * w ----------------
// BM=64, BN=128, BK=64: 1024 active blocks, LDS 24 KB. No min-waves cap.
__global__ __launch_bounds__(256) void moe_gemm2(
    const unsigned short* __restrict__ h_ws, const unsigned short* __restrict__ W2b,
    const int* __restrict__ counts, const int* __restrict__ idxlist,
    const float* __restrict__ wlist, float* __restrict__ contrib,
    float* __restrict__ clsbuf) {
  const int e = blockIdx.z;
  const int count = counts[e * 32];
  const int m0 = blockIdx.y * 64;
  if (m0 >= count) return;
  const int n0 = blockIdx.x * 128;

  __shared__ unsigned short As[64 * 64];    // 8 KB
  __shared__ unsigned short Bs[128 * 64];   // 16 KB

  const int tid = threadIdx.x;
  const int lane = tid & 63;
  const int wave = tid >> 6;
  const int* ilp = idxlist + e * NTOK;

  const int cswz = ((lane & 7) ^ (lane >> 3)) << 3;

  const unsigned short* gA[2]; unsigned short* lA[2];
#pragma unroll
  for (int t = 0; t < 2; ++t) {
    const int rb = (wave << 4) + (t << 3);
    const int r = rb + (lane >> 3);
    const int entry = (m0 + r < count) ? ilp[m0 + r] : 0;
    gA[t] = h_ws + ((size_t)entry << 11) + cswz;
    lA[t] = &As[rb << 6];
  }
  const unsigned short* w2p = W2b + ((size_t)e << 21);
  const unsigned short* gB[4]; unsigned short* lB[4];
#pragma unroll
  for (int t = 0; t < 4; ++t) {
    const int rb = (wave << 5) + (t << 3);
    const int r = rb + (lane >> 3);
    gB[t] = w2p + ((size_t)(n0 + r) << 11) + cswz;
    lB[t] = &Bs[rb << 6];
  }

  const int wm = wave >> 1, wn = wave & 1;
  const int l16 = lane & 15, quad = lane >> 4;
  const int lsw = l16 & 7;

  f32x4 acc[2][4];
  const f32x4 zero = {0.f, 0.f, 0.f, 0.f};
#pragma unroll
  for (int i = 0; i < 2; ++i)
#pragma unroll
    for (int j = 0; j < 4; ++j) acc[i][j] = zero;

  for (int k0 = 0; k0 < HDIM; k0 += 64) {
#pragma unroll
    for (int t = 0; t < 2; ++t) gl_lds16(gA[t] + k0, lA[t]);
#pragma unroll
    for (int t = 0; t < 4; ++t) gl_lds16(gB[t] + k0, lB[t]);
    __syncthreads();
#pragma unroll
    for (int ks = 0; ks < 2; ++ks) {
      const int co = (((ks << 2) + quad) ^ lsw) << 3;
      bf16x8 a[2], b[4];
#pragma unroll
      for (int i = 0; i < 2; ++i) {
        const int row = (wm << 5) + (i << 4) + l16;
        a[i] = *(const bf16x8*)&As[(row << 6) + co];
      }
#pragma unroll
      for (int j = 0; j < 4; ++j) {
        const int row = (wn << 6) + (j << 4) + l16;
        b[j] = *(const bf16x8*)&Bs[(row << 6) + co];
      }
#pragma unroll
      for (int i = 0; i < 2; ++i)
#pragma unroll
        for (int j = 0; j < 4; ++j)
          acc[i][j] = __builtin_amdgcn_mfma_f32_16x16x32_bf16(a[i], b[j], acc[i][j], 0, 0, 0);
    }
    __syncthreads();
  }
#pragma unroll
  for (int i = 0; i < 2; ++i) {
#pragma unroll
    for (int reg = 0; reg < 4; ++reg) {
      const int rl = (wm << 5) + (i << 4) + (quad << 2) + reg;
      if (m0 + rl < count) {
        const int entry = ilp[m0 + rl];          // broadcast within 16 lanes
        const float w = wlist[e * NTOK + m0 + rl];
        const int tok = entry >> 1;
        const bool is_cls = (tok & (SEQ - 1)) == 0;
#pragma unroll
        for (int j = 0; j < 4; ++j) {
          const int col = n0 + (wn << 6) + (j << 4) + l16;
          const float v = acc[i][j][reg] * w;
          contrib[((size_t)entry << 10) + col] = v;
          if (is_cls) clsbuf[(e * 4 + (tok >> 10)) * DDIM + col] = v;
        }
      }
    }
  }
}

// ---------------- Kernel D: combine + expert logits (fused) --------------
__global__ __launch_bounds__(256) void moe_final(
    const float* __restrict__ contrib, float* __restrict__ out_final,
    const float* __restrict__ clsbuf, const float* __restrict__ Wc,
    const float* __restrict__ bcp, float* __restrict__ out_elog) {
  if (blockIdx.x == 4096) {
    __shared__ float t[32];
    const int wave = threadIdx.x >> 6;
    const int lane = threadIdx.x & 63;
    for (int p = wave; p < 32; p += 4) {  // p = e*4 + b
      const float4* vp = (const float4*)(clsbuf + (size_t)p * DDIM + lane * 16);
      const float4* wp = (const float4*)(Wc + lane * 16);
      float a = 0.f;
#pragma unroll
      for (int q = 0; q < 4; ++q) {
        float4 v = vp[q], w = wp[q];
        a += v.x * w.x + v.y * w.y + v.z * w.z + v.w * w.w;
      }
      for (int off = 32; off; off >>= 1) a += __shfl_xor(a, off);
      if (lane == 0) t[p] = a;
    }
    __syncthreads();
    if (threadIdx.x < 4) {
      const int b = threadIdx.x;
      float run = 0.f;
      const float bias = bcp[0];
#pragma unroll
      for (int e = 0; e < NEXP; ++e) {
        run += t[e * 4 + b];
        out_elog[e * 4 + b] = run + bias;
      }
    }
    return;
  }
  const int i = blockIdx.x * 256 + threadIdx.x;  // 1M float4s
  const int tok = i >> 8, c4 = i & 255;
  const float4* cp = (const float4*)contrib;
  float4 a = cp[((size_t)tok * 2) * 256 + c4];
  float4 b = cp[((size_t)tok * 2 + 1) * 256 + c4];
  float4 o; o.x = a.x + b.x; o.y = a.y + b.y; o.z = a.z + b.z; o.w = a.w + b.w;
  ((float4*)out_final)[i] = o;
}

// ---------------- Launch --------------------------------------------------
extern "C" void kernel_launch(void* const* d_in, const int* in_sizes, int n_in,
                              void* d_out, int out_size, void* d_ws, size_t ws_size,
                              hipStream_t stream) {
  const float* x  = (const float*)d_in[0];
  const float* W1 = (const float*)d_in[2];
  const float* W2 = (const float*)d_in[3];
  const float* W3 = (const float*)d_in[4];
  const float* Wg = (const float*)d_in[5];
  const float* Wc = (const float*)d_in[6];
  const float* bc = (const float*)d_in[7];

  float* out_final = (float*)d_out;                  // [4,1024,1024]
  float* out_gate  = out_final + 4194304;            // [4096, 8]
  float* out_elog  = out_gate + 32768;               // [8, 4, 1]
  float* out_rout  = out_elog + 32;                  // [4,1024,8]

  char* ws = (char*)d_ws;
  int*   counts  = (int*)ws;                               // 8 x line-padded ints (1 KB)
  float* clsbuf  = (float*)(ws + 1024);                    // 128 KB
  int*   idxlist = (int*)(ws + 132096);                    // 128 KB
  float* wlist   = (float*)(ws + 263168);                  // 128 KB
  const size_t MB = 1u << 20;
  unsigned short* h_ws = (unsigned short*)(ws + MB);               // 32 MB
  unsigned short* xb   = (unsigned short*)(ws + 33 * MB);          // 8 MB
  unsigned short* W1b  = (unsigned short*)(ws + 41 * MB);          // 32 MB
  unsigned short* W3b  = (unsigned short*)(ws + 73 * MB);          // 32 MB
  unsigned short* W2b  = W1b;                // alias: W1b dead after gemm1
  float* contrib = (float*)(ws + 73 * MB);   // alias: W3b dead after gemm1
  // peak ws use: 105 MB

  hipMemsetAsync(ws, 0, 132096, stream);     // counts + clsbuf (one region)

  moe_prep<<<2304, 256, 0, stream>>>(x, Wg, W1, W3, out_gate, out_rout,
                                     counts, idxlist, wlist, xb, W1b, W3b);
  moe_gemm1<<<dim3(32, 32, 8), 256, 0, stream>>>(xb, W1b, W3b, counts, idxlist, h_ws);
  f2bf_kernel<<<4096, 256, 0, stream>>>(W2, W2b, 2097152);
  moe_gemm2<<<dim3(8, 64, 8), 256, 0, stream>>>(h_ws, W2b, counts, idxlist, wlist,
                                                contrib, clsbuf);
  moe_final<<<4097, 256, 0, stream>>>(contrib, out_final, clsbuf, Wc, bc, out_elog);
}